// Round 13
// baseline (166.757 us; speedup 1.0000x reference)
//
#include <hip/hip_runtime.h>

#define D 32
#define RANGE 128        // nodes per range; R = ceil(n/RANGE) = 782
#define RMAX 800         // LDS counter capacity (>= R)
#define JC 512           // edge chunks == blockDim of consumers' segment loops
#define CHUNKMAX 3200    // LDS record capacity per sort block (chunk = 3126)
#define CAP 2560         // gather LDS record capacity per range (mean 2048, +11 sigma)

// ---- K1: per-chunk LDS counting-sort by range; chunk-contiguous coalesced
// write-out; publishes meta[j][r] = localStart<<16 | count for both streams.
// dst rec = (s | dl<<17, ef_masked). src rec = s.
__global__ __launch_bounds__(512) void sort_chunks(
        const int* __restrict__ src, const int* __restrict__ dst,
        const float* __restrict__ ef,
        uint2* __restrict__ recs, unsigned* __restrict__ recsS,
        unsigned* __restrict__ metaD, unsigned* __restrict__ metaS,
        int E, int R, int chunk) {
    __shared__ uint2 sd[CHUNKMAX];           // 25.6 KB sorted dst records
    __shared__ unsigned ss_[CHUNKMAX];       // 12.8 KB sorted src ids
    __shared__ int cd[RMAX], cs[RMAX];       // per-range counts
    __shared__ int curD[RMAX], curS[RMAX];   // scan / cursors
    int j = blockIdx.x, t = threadIdx.x;
    int e0 = j * chunk, e1 = min(E, e0 + chunk), cntE = e1 - e0;
    for (int i = t; i < RMAX; i += 512) { cd[i] = 0; cs[i] = 0; }
    __syncthreads();
    // pass 1: count per-range
    for (int e = e0 + 2 * t; e < e1; e += 1024) {
        if (e + 1 < e1) {
            int2 s2 = *(const int2*)(src + e);
            int2 d2 = *(const int2*)(dst + e);
            atomicAdd(&cd[d2.x >> 7], 1);
            atomicAdd(&cd[d2.y >> 7], 1);
            atomicAdd(&cs[s2.x >> 7], 1);
            atomicAdd(&cs[s2.y >> 7], 1);
        } else {
            atomicAdd(&cd[dst[e] >> 7], 1);
            atomicAdd(&cs[src[e] >> 7], 1);
        }
    }
    __syncthreads();
    // Hillis-Steele inclusive scan (RMAX entries, 2 per thread) -> exclusive cursors
    {
        int i1 = t + 512;
        curD[t] = cd[t]; curS[t] = cs[t];
        if (i1 < RMAX) { curD[i1] = cd[i1]; curS[i1] = cs[i1]; }
        __syncthreads();
        for (int off = 1; off < RMAX; off <<= 1) {
            int vD0 = (t >= off) ? curD[t - off] : 0;
            int vS0 = (t >= off) ? curS[t - off] : 0;
            int vD1 = 0, vS1 = 0;
            if (i1 < RMAX && i1 >= off) { vD1 = curD[i1 - off]; vS1 = curS[i1 - off]; }
            __syncthreads();
            curD[t] += vD0; curS[t] += vS0;
            if (i1 < RMAX) { curD[i1] += vD1; curS[i1] += vS1; }
            __syncthreads();
        }
        curD[t] -= cd[t]; curS[t] -= cs[t];
        if (i1 < RMAX) { curD[i1] -= cd[i1]; curS[i1] -= cs[i1]; }
        __syncthreads();
    }
    // pass 2: place into LDS sorted by range
    for (int e = e0 + t; e < e1; e += 512) {
        int s = src[e], d = dst[e];
        float w = (s == d) ? 0.0f : ef[e];
        int pos = atomicAdd(&curD[d >> 7], 1);
        sd[pos] = make_uint2((unsigned)s | ((unsigned)(d & (RANGE - 1)) << 17),
                             __float_as_uint(w));
        int ps = atomicAdd(&curS[s >> 7], 1);
        ss_[ps] = (unsigned)s;
    }
    __syncthreads();
    // coalesced chunk-contiguous write-out
    size_t baseE = (size_t)j * chunk;
    for (int i = t; i < cntE; i += 512) {
        recs[baseE + i] = sd[i];
        recsS[baseE + i] = ss_[i];
    }
    // meta (start and count both <= 3126, fit 16 bits); curD now == start+count
    for (int i = t; i < R; i += 512) {
        metaD[(size_t)j * R + i] = ((unsigned)(curD[i] - cd[i]) << 16) | (unsigned)cd[i];
        metaS[(size_t)j * R + i] = ((unsigned)(curS[i] - cs[i]) << 16) | (unsigned)cs[i];
    }
}

// ---- K2: per-range out-degree count from src segments + pre-scaled bf16 rows. ----
__device__ __forceinline__ unsigned short f2bf(float x) {
    unsigned u = __float_as_uint(x);
    u += 0x7FFFu + ((u >> 16) & 1u);
    return (unsigned short)(u >> 16);
}

__global__ __launch_bounds__(512) void srcnorm_convert(
        const unsigned* __restrict__ recsS, const unsigned* __restrict__ metaS,
        const float* __restrict__ feat, unsigned short* __restrict__ featb,
        int n, int R, int chunk) {
    __shared__ int cnt[RANGE];
    int r = blockIdx.x, t = threadIdx.x;
    int base = r * RANGE, lim = min(n - base, RANGE);
    if (t < RANGE) cnt[t] = 0;
    __syncthreads();
    // thread t handles chunk j == t (JC == 512 == blockDim)
    unsigned m = metaS[(size_t)t * R + r];
    int st = m >> 16, c = m & 0xFFFFu;
    const unsigned* p = recsS + (size_t)t * chunk + st;
    for (int k = 0; k < c; k++) atomicAdd(&cnt[p[k] - (unsigned)base], 1);
    __syncthreads();
    int total4 = lim * 8;   // 8 float4 chunks per row
    for (int i = t; i < total4; i += 512) {
        int row = i >> 3;
        float sn = rsqrtf((float)max(cnt[row], 1));
        float4 f = ((const float4*)(feat + (size_t)(base + row) * D))[i & 7];
        ushort4 u;
        u.x = f2bf(f.x * sn); u.y = f2bf(f.y * sn);
        u.z = f2bf(f.z * sn); u.w = f2bf(f.w * sn);
        ((ushort4*)(featb + (size_t)(base + row) * D))[i & 7] = u;
    }
}

// ---- K3: direct global->LDS node-sort (count pass + place pass, no staging
// buffer) -> register gather + output. LDS ~22 KB -> 4 blocks/CU (100% waves).
__global__ __launch_bounds__(512) void gather_kernel(
        const float* __restrict__ feat, const unsigned short* __restrict__ featb,
        const uint2* __restrict__ recs, const unsigned* __restrict__ metaD,
        float* __restrict__ out, int n, int R, int chunk) {
    __shared__ uint2 srec[CAP];          // 20.5 KB node-sorted records
    __shared__ int indeg[RANGE];
    __shared__ int pre[RANGE + 1];
    __shared__ int cur[RANGE];
    int r = blockIdx.x, t = threadIdx.x;
    int base = r * RANGE, lim = min(n - base, RANGE);
    unsigned m = metaD[(size_t)t * R + r];    // thread t owns chunk j == t
    int st = m >> 16, c = m & 0xFFFFu;
    const uint2* p = recs + (size_t)t * chunk + st;
    if (t < RANGE) indeg[t] = 0;
    __syncthreads();
    // pass A: count in-degrees from my segment
    for (int k = 0; k < c; k++) atomicAdd(&indeg[p[k].x >> 17], 1);
    __syncthreads();
    // node-count prefix scan (RANGE = 128)
    if (t < RANGE) pre[t + 1] = indeg[t];
    if (t == 0) pre[0] = 0;
    __syncthreads();
    for (int off = 1; off < RANGE; off <<= 1) {
        int v = 0;
        if (t < RANGE) { int idx = t + 1; if (idx > off) v = pre[idx - off]; }
        __syncthreads();
        if (t < RANGE) pre[t + 1] += v;
        __syncthreads();
    }
    if (t < RANGE) cur[t] = pre[t];
    __syncthreads();
    int total = pre[RANGE];
    bool ovf = total > CAP;
    // pass B: re-read segment (L2-hot), place into srec sorted by node
    if (!ovf) {
        for (int k = 0; k < c; k++) {
            uint2 rec = p[k];
            int pos = atomicAdd(&cur[(int)(rec.x >> 17)], 1);
            srec[pos] = make_uint2(rec.x & 0x1FFFFu, rec.y);
        }
    }
    __syncthreads();
    // gather: 4 lanes per node, 16B bf16 chunks, register accumulation
    int node = t >> 2;
    int cch = t & 3;
    if (node >= lim) return;
    int p0i = pre[node];
    int cnt = pre[node + 1] - p0i;
    float a0 = 0.f, a1 = 0.f, a2 = 0.f, a3 = 0.f, a4 = 0.f, a5 = 0.f, a6 = 0.f, a7 = 0.f;
    if (!ovf) {
        int i = 0;
        for (; i + 2 <= cnt; i += 2) {
            uint2 q0 = srec[p0i + i];
            uint2 q1 = srec[p0i + i + 1];
            uint4 b0 = ((const uint4*)(featb + (size_t)q0.x * D))[cch];
            uint4 b1 = ((const uint4*)(featb + (size_t)q1.x * D))[cch];
            float w0 = __uint_as_float(q0.y);
            float w1 = __uint_as_float(q1.y);
            a0 += __uint_as_float(b0.x << 16) * w0 + __uint_as_float(b1.x << 16) * w1;
            a1 += __uint_as_float(b0.x & 0xFFFF0000u) * w0 + __uint_as_float(b1.x & 0xFFFF0000u) * w1;
            a2 += __uint_as_float(b0.y << 16) * w0 + __uint_as_float(b1.y << 16) * w1;
            a3 += __uint_as_float(b0.y & 0xFFFF0000u) * w0 + __uint_as_float(b1.y & 0xFFFF0000u) * w1;
            a4 += __uint_as_float(b0.z << 16) * w0 + __uint_as_float(b1.z << 16) * w1;
            a5 += __uint_as_float(b0.z & 0xFFFF0000u) * w0 + __uint_as_float(b1.z & 0xFFFF0000u) * w1;
            a6 += __uint_as_float(b0.w << 16) * w0 + __uint_as_float(b1.w << 16) * w1;
            a7 += __uint_as_float(b0.w & 0xFFFF0000u) * w0 + __uint_as_float(b1.w & 0xFFFF0000u) * w1;
        }
        if (i < cnt) {
            uint2 q = srec[p0i + i];
            uint4 b = ((const uint4*)(featb + (size_t)q.x * D))[cch];
            float w = __uint_as_float(q.y);
            a0 += __uint_as_float(b.x << 16) * w;
            a1 += __uint_as_float(b.x & 0xFFFF0000u) * w;
            a2 += __uint_as_float(b.y << 16) * w;
            a3 += __uint_as_float(b.y & 0xFFFF0000u) * w;
            a4 += __uint_as_float(b.z << 16) * w;
            a5 += __uint_as_float(b.z & 0xFFFF0000u) * w;
            a6 += __uint_as_float(b.w << 16) * w;
            a7 += __uint_as_float(b.w & 0xFFFF0000u) * w;
        }
    } else {
        // overflow fallback: direct scan of all segments (statistically never taken)
        for (int j = 0; j < JC; j++) {
            unsigned mm = metaD[(size_t)j * R + r];
            const uint2* pp = recs + (size_t)j * chunk + (mm >> 16);
            int cc = mm & 0xFFFFu;
            for (int k = 0; k < cc; k++) {
                uint2 rec = pp[k];
                if ((int)(rec.x >> 17) == node) {
                    uint4 b = ((const uint4*)(featb + (size_t)(rec.x & 0x1FFFFu) * D))[cch];
                    float w = __uint_as_float(rec.y);
                    a0 += __uint_as_float(b.x << 16) * w;
                    a1 += __uint_as_float(b.x & 0xFFFF0000u) * w;
                    a2 += __uint_as_float(b.y << 16) * w;
                    a3 += __uint_as_float(b.y & 0xFFFF0000u) * w;
                    a4 += __uint_as_float(b.z << 16) * w;
                    a5 += __uint_as_float(b.z & 0xFFFF0000u) * w;
                    a6 += __uint_as_float(b.w << 16) * w;
                    a7 += __uint_as_float(b.w & 0xFFFF0000u) * w;
                }
            }
        }
    }
    float dn = rsqrtf((float)max(cnt, 1));
    const float4* fr = (const float4*)(feat + (size_t)(base + node) * D);
    float4 fA = fr[cch * 2];
    float4 fB = fr[cch * 2 + 1];
    float v = fabsf(fA.x - a0 * dn) + fabsf(fA.y - a1 * dn) +
              fabsf(fA.z - a2 * dn) + fabsf(fA.w - a3 * dn) +
              fabsf(fB.x - a4 * dn) + fabsf(fB.y - a5 * dn) +
              fabsf(fB.z - a6 * dn) + fabsf(fB.w - a7 * dn);
    v += __shfl_xor(v, 1, 4);
    v += __shfl_xor(v, 2, 4);
    if (cch == 0) out[base + node] = v;
}

extern "C" void kernel_launch(void* const* d_in, const int* in_sizes, int n_in,
                              void* d_out, int out_size, void* d_ws, size_t ws_size,
                              hipStream_t stream) {
    const float* feat   = (const float*)d_in[0];
    const float* e_feat = (const float*)d_in[1];
    const int*   src    = (const int*)d_in[2];
    const int*   dst    = (const int*)d_in[3];
    const int E = in_sizes[2];
    const int n = in_sizes[0] / D;
    float* out = (float*)d_out;

    const int R = (n + RANGE - 1) / RANGE;              // 782
    const int chunk = (((E + JC - 1) / JC) + 1) & ~1;   // 3126 (even, <= CHUNKMAX, < 65536)

    // ws layout (16B-aligned; every cell written before read — no memset needed):
    //   recs[JC*chunk] uint2 | recsS[JC*chunk] uint |
    //   metaD[JC*R] uint | metaS[JC*R] uint | featb[n*D] ushort
    char* p = (char*)d_ws;
    uint2* recs    = (uint2*)p;    p += ((size_t)JC * chunk * 8 + 15) & ~(size_t)15;
    unsigned* recsS = (unsigned*)p; p += ((size_t)JC * chunk * 4 + 15) & ~(size_t)15;
    unsigned* metaD = (unsigned*)p; p += ((size_t)JC * R * 4 + 15) & ~(size_t)15;
    unsigned* metaS = (unsigned*)p; p += ((size_t)JC * R * 4 + 15) & ~(size_t)15;
    unsigned short* featb = (unsigned short*)p;

    sort_chunks<<<JC, 512, 0, stream>>>(src, dst, e_feat, recs, recsS, metaD, metaS,
                                        E, R, chunk);

    srcnorm_convert<<<R, 512, 0, stream>>>(recsS, metaS, feat, featb, n, R, chunk);

    gather_kernel<<<R, 512, 0, stream>>>(feat, featb, recs, metaD, out, n, R, chunk);
}

// Round 14
// 144.801 us; speedup vs baseline: 1.1516x; 1.1516x over previous
//
#include <hip/hip_runtime.h>

#define D 32
#define RANGE 128        // nodes per range; R = ceil(n/RANGE) = 782
#define RMAX 800         // LDS counter capacity (>= R)
#define JC 512           // edge chunks == blockDim of consumers' segment loops
#define CHUNKMAX 3200    // LDS record capacity per sort block (chunk = 3126)
#define CAP 2304         // gather LDS record capacity per range (mean 2048, +5.7 sigma)
                         // 16*CAP + ~3.6KB LDS = ~40KB -> 4 blocks/CU (100% wave cap)

// ---- K1: per-chunk LDS counting-sort by range; chunk-contiguous coalesced
// write-out; publishes meta[j][r] = localStart<<16 | count for both streams.
// dst rec = (s | dl<<17, ef_masked). src rec = s.
__global__ __launch_bounds__(512) void sort_chunks(
        const int* __restrict__ src, const int* __restrict__ dst,
        const float* __restrict__ ef,
        uint2* __restrict__ recs, unsigned* __restrict__ recsS,
        unsigned* __restrict__ metaD, unsigned* __restrict__ metaS,
        int E, int R, int chunk) {
    __shared__ uint2 sd[CHUNKMAX];           // 25.6 KB sorted dst records
    __shared__ unsigned ss_[CHUNKMAX];       // 12.8 KB sorted src ids
    __shared__ int cd[RMAX], cs[RMAX];       // per-range counts
    __shared__ int curD[RMAX], curS[RMAX];   // scan / cursors
    int j = blockIdx.x, t = threadIdx.x;
    int e0 = j * chunk, e1 = min(E, e0 + chunk), cntE = e1 - e0;
    for (int i = t; i < RMAX; i += 512) { cd[i] = 0; cs[i] = 0; }
    __syncthreads();
    // pass 1: count per-range
    for (int e = e0 + 2 * t; e < e1; e += 1024) {
        if (e + 1 < e1) {
            int2 s2 = *(const int2*)(src + e);
            int2 d2 = *(const int2*)(dst + e);
            atomicAdd(&cd[d2.x >> 7], 1);
            atomicAdd(&cd[d2.y >> 7], 1);
            atomicAdd(&cs[s2.x >> 7], 1);
            atomicAdd(&cs[s2.y >> 7], 1);
        } else {
            atomicAdd(&cd[dst[e] >> 7], 1);
            atomicAdd(&cs[src[e] >> 7], 1);
        }
    }
    __syncthreads();
    // Hillis-Steele inclusive scan (RMAX entries, 2 per thread) -> exclusive cursors
    {
        int i1 = t + 512;
        curD[t] = cd[t]; curS[t] = cs[t];
        if (i1 < RMAX) { curD[i1] = cd[i1]; curS[i1] = cs[i1]; }
        __syncthreads();
        for (int off = 1; off < RMAX; off <<= 1) {
            int vD0 = (t >= off) ? curD[t - off] : 0;
            int vS0 = (t >= off) ? curS[t - off] : 0;
            int vD1 = 0, vS1 = 0;
            if (i1 < RMAX && i1 >= off) { vD1 = curD[i1 - off]; vS1 = curS[i1 - off]; }
            __syncthreads();
            curD[t] += vD0; curS[t] += vS0;
            if (i1 < RMAX) { curD[i1] += vD1; curS[i1] += vS1; }
            __syncthreads();
        }
        curD[t] -= cd[t]; curS[t] -= cs[t];
        if (i1 < RMAX) { curD[i1] -= cd[i1]; curS[i1] -= cs[i1]; }
        __syncthreads();
    }
    // pass 2: place into LDS sorted by range
    for (int e = e0 + t; e < e1; e += 512) {
        int s = src[e], d = dst[e];
        float w = (s == d) ? 0.0f : ef[e];
        int pos = atomicAdd(&curD[d >> 7], 1);
        sd[pos] = make_uint2((unsigned)s | ((unsigned)(d & (RANGE - 1)) << 17),
                             __float_as_uint(w));
        int ps = atomicAdd(&curS[s >> 7], 1);
        ss_[ps] = (unsigned)s;
    }
    __syncthreads();
    // coalesced chunk-contiguous write-out
    size_t baseE = (size_t)j * chunk;
    for (int i = t; i < cntE; i += 512) {
        recs[baseE + i] = sd[i];
        recsS[baseE + i] = ss_[i];
    }
    // meta (start and count both <= 3126, fit 16 bits); curD now == start+count
    for (int i = t; i < R; i += 512) {
        metaD[(size_t)j * R + i] = ((unsigned)(curD[i] - cd[i]) << 16) | (unsigned)cd[i];
        metaS[(size_t)j * R + i] = ((unsigned)(curS[i] - cs[i]) << 16) | (unsigned)cs[i];
    }
}

// ---- K2: per-range out-degree count from src segments + pre-scaled bf16 rows. ----
__device__ __forceinline__ unsigned short f2bf(float x) {
    unsigned u = __float_as_uint(x);
    u += 0x7FFFu + ((u >> 16) & 1u);
    return (unsigned short)(u >> 16);
}

__global__ __launch_bounds__(512) void srcnorm_convert(
        const unsigned* __restrict__ recsS, const unsigned* __restrict__ metaS,
        const float* __restrict__ feat, unsigned short* __restrict__ featb,
        int n, int R, int chunk) {
    __shared__ int cnt[RANGE];
    int r = blockIdx.x, t = threadIdx.x;
    int base = r * RANGE, lim = min(n - base, RANGE);
    if (t < RANGE) cnt[t] = 0;
    __syncthreads();
    // thread t handles chunk j == t (JC == 512 == blockDim)
    unsigned m = metaS[(size_t)t * R + r];
    int st = m >> 16, c = m & 0xFFFFu;
    const unsigned* p = recsS + (size_t)t * chunk + st;
    for (int k = 0; k < c; k++) atomicAdd(&cnt[p[k] - (unsigned)base], 1);
    __syncthreads();
    int total4 = lim * 8;   // 8 float4 chunks per row
    for (int i = t; i < total4; i += 512) {
        int row = i >> 3;
        float sn = rsqrtf((float)max(cnt[row], 1));
        float4 f = ((const float4*)(feat + (size_t)(base + row) * D))[i & 7];
        ushort4 u;
        u.x = f2bf(f.x * sn); u.y = f2bf(f.y * sn);
        u.z = f2bf(f.z * sn); u.w = f2bf(f.w * sn);
        ((ushort4*)(featb + (size_t)(base + row) * D))[i & 7] = u;
    }
}

// ---- K3: per-range segment collect -> LDS node-sort -> register gather + output.
// Single segment read (staged via raw), ~40KB LDS -> 4 blocks/CU, 4x unrolled gather.
__global__ __launch_bounds__(512) void gather_kernel(
        const float* __restrict__ feat, const unsigned short* __restrict__ featb,
        const uint2* __restrict__ recs, const unsigned* __restrict__ metaD,
        float* __restrict__ out, int n, int R, int chunk) {
    __shared__ uint2 raw[CAP];           // 18 KB segment-appended records
    __shared__ uint2 srec[CAP];          // 18 KB node-sorted records
    __shared__ int segpre[JC + 1];       // 2 KB segment-count prefix
    __shared__ int indeg[RANGE];         // counts, then reused as sort cursors
    __shared__ int pre[RANGE + 1];
    int r = blockIdx.x, t = threadIdx.x;
    int base = r * RANGE, lim = min(n - base, RANGE);
    unsigned m = metaD[(size_t)t * R + r];    // thread t owns chunk j == t
    int st = m >> 16, c = m & 0xFFFFu;
    segpre[t + 1] = c;
    if (t == 0) segpre[0] = 0;
    if (t < RANGE) indeg[t] = 0;
    __syncthreads();
    // Hillis-Steele inclusive scan over 512 segment counts
    for (int off = 1; off < JC; off <<= 1) {
        int v = (t + 1 > off) ? segpre[t + 1 - off] : 0;
        __syncthreads();
        segpre[t + 1] += v;
        __syncthreads();
    }
    int total = segpre[JC];
    bool ovf = total > CAP;
    // collect my segment into raw + count in-degrees (single global segment read)
    const uint2* p = recs + (size_t)t * chunk + st;
    if (!ovf) {
        int dp = segpre[t];
        for (int k = 0; k < c; k++) {
            uint2 rec = p[k];
            raw[dp + k] = rec;
            atomicAdd(&indeg[rec.x >> 17], 1);
        }
    } else {
        for (int k = 0; k < c; k++) atomicAdd(&indeg[p[k].x >> 17], 1);
    }
    __syncthreads();
    // node-count prefix scan (RANGE = 128)
    if (t < RANGE) pre[t + 1] = indeg[t];
    if (t == 0) pre[0] = 0;
    __syncthreads();
    for (int off = 1; off < RANGE; off <<= 1) {
        int v = 0;
        if (t < RANGE) { int idx = t + 1; if (idx > off) v = pre[idx - off]; }
        __syncthreads();
        if (t < RANGE) pre[t + 1] += v;
        __syncthreads();
    }
    if (t < RANGE) indeg[t] = pre[t];   // reuse indeg as sort cursors
    __syncthreads();
    // sort raw -> srec by node
    if (!ovf) {
        for (int i = t; i < total; i += 512) {
            uint2 rec = raw[i];
            int dl = rec.x >> 17;
            int pos = atomicAdd(&indeg[dl], 1);
            srec[pos] = make_uint2(rec.x & 0x1FFFFu, rec.y);
        }
    }
    __syncthreads();
    // gather: 4 lanes per node, 16B bf16 chunks, 4x unrolled register accumulation
    int node = t >> 2;
    int cch = t & 3;
    if (node >= lim) return;
    int p0i = pre[node];
    int cnt = pre[node + 1] - p0i;
    float a0 = 0.f, a1 = 0.f, a2 = 0.f, a3 = 0.f, a4 = 0.f, a5 = 0.f, a6 = 0.f, a7 = 0.f;
    if (!ovf) {
        const uint2* sp = srec + p0i;
        int i = 0;
        for (; i + 4 <= cnt; i += 4) {
            uint2 q0 = sp[i], q1 = sp[i + 1], q2 = sp[i + 2], q3 = sp[i + 3];
            uint4 b0 = ((const uint4*)(featb + (size_t)q0.x * D))[cch];
            uint4 b1 = ((const uint4*)(featb + (size_t)q1.x * D))[cch];
            uint4 b2 = ((const uint4*)(featb + (size_t)q2.x * D))[cch];
            uint4 b3 = ((const uint4*)(featb + (size_t)q3.x * D))[cch];
            float w0 = __uint_as_float(q0.y), w1 = __uint_as_float(q1.y);
            float w2 = __uint_as_float(q2.y), w3 = __uint_as_float(q3.y);
            a0 += __uint_as_float(b0.x << 16) * w0 + __uint_as_float(b1.x << 16) * w1
                + __uint_as_float(b2.x << 16) * w2 + __uint_as_float(b3.x << 16) * w3;
            a1 += __uint_as_float(b0.x & 0xFFFF0000u) * w0 + __uint_as_float(b1.x & 0xFFFF0000u) * w1
                + __uint_as_float(b2.x & 0xFFFF0000u) * w2 + __uint_as_float(b3.x & 0xFFFF0000u) * w3;
            a2 += __uint_as_float(b0.y << 16) * w0 + __uint_as_float(b1.y << 16) * w1
                + __uint_as_float(b2.y << 16) * w2 + __uint_as_float(b3.y << 16) * w3;
            a3 += __uint_as_float(b0.y & 0xFFFF0000u) * w0 + __uint_as_float(b1.y & 0xFFFF0000u) * w1
                + __uint_as_float(b2.y & 0xFFFF0000u) * w2 + __uint_as_float(b3.y & 0xFFFF0000u) * w3;
            a4 += __uint_as_float(b0.z << 16) * w0 + __uint_as_float(b1.z << 16) * w1
                + __uint_as_float(b2.z << 16) * w2 + __uint_as_float(b3.z << 16) * w3;
            a5 += __uint_as_float(b0.z & 0xFFFF0000u) * w0 + __uint_as_float(b1.z & 0xFFFF0000u) * w1
                + __uint_as_float(b2.z & 0xFFFF0000u) * w2 + __uint_as_float(b3.z & 0xFFFF0000u) * w3;
            a6 += __uint_as_float(b0.w << 16) * w0 + __uint_as_float(b1.w << 16) * w1
                + __uint_as_float(b2.w << 16) * w2 + __uint_as_float(b3.w << 16) * w3;
            a7 += __uint_as_float(b0.w & 0xFFFF0000u) * w0 + __uint_as_float(b1.w & 0xFFFF0000u) * w1
                + __uint_as_float(b2.w & 0xFFFF0000u) * w2 + __uint_as_float(b3.w & 0xFFFF0000u) * w3;
        }
        for (; i < cnt; i++) {
            uint2 q = sp[i];
            uint4 b = ((const uint4*)(featb + (size_t)q.x * D))[cch];
            float w = __uint_as_float(q.y);
            a0 += __uint_as_float(b.x << 16) * w;
            a1 += __uint_as_float(b.x & 0xFFFF0000u) * w;
            a2 += __uint_as_float(b.y << 16) * w;
            a3 += __uint_as_float(b.y & 0xFFFF0000u) * w;
            a4 += __uint_as_float(b.z << 16) * w;
            a5 += __uint_as_float(b.z & 0xFFFF0000u) * w;
            a6 += __uint_as_float(b.w << 16) * w;
            a7 += __uint_as_float(b.w & 0xFFFF0000u) * w;
        }
    } else {
        // overflow fallback: direct scan of all segments (statistically never taken)
        for (int j = 0; j < JC; j++) {
            unsigned mm = metaD[(size_t)j * R + r];
            const uint2* pp = recs + (size_t)j * chunk + (mm >> 16);
            int cc = mm & 0xFFFFu;
            for (int k = 0; k < cc; k++) {
                uint2 rec = pp[k];
                if ((int)(rec.x >> 17) == node) {
                    uint4 b = ((const uint4*)(featb + (size_t)(rec.x & 0x1FFFFu) * D))[cch];
                    float w = __uint_as_float(rec.y);
                    a0 += __uint_as_float(b.x << 16) * w;
                    a1 += __uint_as_float(b.x & 0xFFFF0000u) * w;
                    a2 += __uint_as_float(b.y << 16) * w;
                    a3 += __uint_as_float(b.y & 0xFFFF0000u) * w;
                    a4 += __uint_as_float(b.z << 16) * w;
                    a5 += __uint_as_float(b.z & 0xFFFF0000u) * w;
                    a6 += __uint_as_float(b.w << 16) * w;
                    a7 += __uint_as_float(b.w & 0xFFFF0000u) * w;
                }
            }
        }
    }
    float dn = rsqrtf((float)max(cnt, 1));
    const float4* fr = (const float4*)(feat + (size_t)(base + node) * D);
    float4 fA = fr[cch * 2];
    float4 fB = fr[cch * 2 + 1];
    float v = fabsf(fA.x - a0 * dn) + fabsf(fA.y - a1 * dn) +
              fabsf(fA.z - a2 * dn) + fabsf(fA.w - a3 * dn) +
              fabsf(fB.x - a4 * dn) + fabsf(fB.y - a5 * dn) +
              fabsf(fB.z - a6 * dn) + fabsf(fB.w - a7 * dn);
    v += __shfl_xor(v, 1, 4);
    v += __shfl_xor(v, 2, 4);
    if (cch == 0) out[base + node] = v;
}

extern "C" void kernel_launch(void* const* d_in, const int* in_sizes, int n_in,
                              void* d_out, int out_size, void* d_ws, size_t ws_size,
                              hipStream_t stream) {
    const float* feat   = (const float*)d_in[0];
    const float* e_feat = (const float*)d_in[1];
    const int*   src    = (const int*)d_in[2];
    const int*   dst    = (const int*)d_in[3];
    const int E = in_sizes[2];
    const int n = in_sizes[0] / D;
    float* out = (float*)d_out;

    const int R = (n + RANGE - 1) / RANGE;              // 782
    const int chunk = (((E + JC - 1) / JC) + 1) & ~1;   // 3126 (even, <= CHUNKMAX, < 65536)

    // ws layout (16B-aligned; every cell written before read — no memset needed):
    //   recs[JC*chunk] uint2 | recsS[JC*chunk] uint |
    //   metaD[JC*R] uint | metaS[JC*R] uint | featb[n*D] ushort
    char* p = (char*)d_ws;
    uint2* recs    = (uint2*)p;    p += ((size_t)JC * chunk * 8 + 15) & ~(size_t)15;
    unsigned* recsS = (unsigned*)p; p += ((size_t)JC * chunk * 4 + 15) & ~(size_t)15;
    unsigned* metaD = (unsigned*)p; p += ((size_t)JC * R * 4 + 15) & ~(size_t)15;
    unsigned* metaS = (unsigned*)p; p += ((size_t)JC * R * 4 + 15) & ~(size_t)15;
    unsigned short* featb = (unsigned short*)p;

    sort_chunks<<<JC, 512, 0, stream>>>(src, dst, e_feat, recs, recsS, metaD, metaS,
                                        E, R, chunk);

    srcnorm_convert<<<R, 512, 0, stream>>>(recsS, metaS, feat, featb, n, R, chunk);

    gather_kernel<<<R, 512, 0, stream>>>(feat, featb, recs, metaD, out, n, R, chunk);
}